// Round 11
// baseline (70.569 us; speedup 1.0000x reference)
//
#include <hip/hip_runtime.h>

#define LSEQ 4096
#define GRID 2048  // 2 t per block

typedef __bf16 bf16x8 __attribute__((ext_vector_type(8)));
typedef float f32x16 __attribute__((ext_vector_type(16)));
typedef unsigned u32x4 __attribute__((ext_vector_type(4)));

union FU { unsigned u[4]; u32x4 uv; bf16x8 v; };
union FX { u32x4 uv; float f[4]; };

__device__ __forceinline__ unsigned short bfb(float f) {
  __bf16 h = (__bf16)f;
  return __builtin_bit_cast(unsigned short, h);
}
__device__ __forceinline__ unsigned pk2(float a, float b) {
  return (unsigned)bfb(a) | ((unsigned)bfb(b) << 16);
}
// Half-exchange across lane 32 boundary — R7's verified ds_bpermute form.
__device__ __forceinline__ void xchg(unsigned P0, unsigned P1, unsigned P2, unsigned P3,
                                     const int hi, unsigned o[4]) {
  const unsigned sA = hi ? P0 : P2, sB = hi ? P1 : P3;
  const unsigned rA = __shfl_xor(sA, 32), rB = __shfl_xor(sB, 32);
  o[0] = hi ? rA : P0; o[1] = hi ? rB : P1;
  o[2] = hi ? P2 : rA; o[3] = hi ? P3 : rB;
}

// ALL global loads in fused_mha go through asm so vmcnt inventory is exact.
__device__ __forceinline__ u32x4 gload(const void* p) {
  u32x4 d;
  asm volatile("global_load_dwordx4 %0, %1, off" : "=v"(d) : "v"(p));
  return d;
}
#define WAITV(n)                                              \
  do {                                                        \
    asm volatile("s_waitcnt vmcnt(" #n ")" ::: "memory");     \
    __builtin_amdgcn_sched_barrier(0);                        \
  } while (0)
#define WAITL                                                 \
  do {                                                        \
    asm volatile("s_waitcnt lgkmcnt(0)" ::: "memory");        \
    __builtin_amdgcn_sched_barrier(0);                        \
  } while (0)

// Repack weights to fragment order in ws (unchanged since round 3).
__global__ __launch_bounds__(64) void repack(
    const float* __restrict__ Wv, const float* __restrict__ bv,
    const float* __restrict__ Wk, const float* __restrict__ bk,
    const float* __restrict__ Wq, const float* __restrict__ bq,
    const float* __restrict__ Wo, const float* __restrict__ bo,
    u32x4* __restrict__ ws) {
  const int b = blockIdx.x;  // 144 = 4 mats * 4 nt * 9 ks
  const int ks = b % 9, nt = (b / 9) & 3, m = b / 36;
  const float* Ws[4] = {Wv, Wk, Wq, Wo};
  const float* Bs[4] = {bv, bk, bq, bo};
  const int l = threadIdx.x, l31 = l & 31, hi = l >> 5;
  FU f;
  if (ks < 8) {
#pragma unroll
    for (int e = 0; e < 4; ++e) {
      const float a = Ws[m][(ks * 16 + hi * 8 + 2 * e) * 128 + nt * 32 + l31];
      const float c = Ws[m][(ks * 16 + hi * 8 + 2 * e + 1) * 128 + nt * 32 + l31];
      f.u[e] = pk2(a, c);
    }
  } else {
    f.u[0] = (hi == 0) ? (unsigned)bfb(Bs[m][nt * 32 + l31]) : 0u;
    f.u[1] = 0; f.u[2] = 0; f.u[3] = 0;
  }
  ws[b * 64 + l] = f.uv;
}

// 8 waves / 2 sequence positions per block: wave wid handles (ts = wid>>2,
// nt = wid&3), t = 2*bid + ts. Per-wave pipeline is EXACTLY round 7's
// verified ledger: [X12,A9] W(9) stage | B9 W(9)=A Vproj | C9 W(9)=B Kproj |
// D9 W(9)=C Qproj | attn | W(0)=D Oproj.  LDS 64KB -> 2 blocks/CU resident
// = 16 waves/CU (vs 11 at the 256-thread decomposition).
__global__ __launch_bounds__(512, 4) void fused_mha(
    const float* __restrict__ Xv, const float* __restrict__ Xk, const float* __restrict__ Xq,
    const u32x4* __restrict__ wf4, float* __restrict__ out) {
  __shared__ u32x4 xlds[2][3 * 8 * 64];  // 48KB: [ts][tau][ks][lane^ks]
  __shared__ u32x4 olds[2][8 * 64];      // 16KB: [ts][h][lane]
  const int tid = threadIdx.x;
  const int wid = tid >> 6, l = tid & 63;
  const int ts = wid >> 2, nt = wid & 3, l31 = l & 31, hi = l >> 5;
  const int sts = tid >> 8, rr = (tid >> 3) & 31, ksc = tid & 7;
  const int t = (blockIdx.x << 1) + ts;
  const int tstage = (blockIdx.x << 1) + sts;
  const float* Xs[3] = {Xv, Xk, Xq};

  // ---- issue X loads (12/thread) then wfA (mat0): outstanding = 21 ----
  u32x4 xr[12];
  {
#pragma unroll
    for (int tau = 0; tau < 3; ++tau) {
      const float* bp = Xs[tau] + ((long)rr * LSEQ + tstage) * 128 + ksc * 16;
#pragma unroll
      for (int i = 0; i < 4; ++i) xr[tau * 4 + i] = gload(bp + i * 4);
    }
  }
  FU wfA[9], wfB[9], wfC[9], wfD[9];
  {
    const u32x4* wb = wf4 + ((0 * 4 + nt) * 9) * 64 + l;
#pragma unroll
    for (int ks = 0; ks < 9; ++ks) wfA[ks].uv = gload(wb + ks * 64);
  }

  WAITV(9);  // X drained (oldest 12); wfA still in flight
  {
#pragma unroll
    for (int tau = 0; tau < 3; ++tau) {
      FX a, b, c, d;
      a.uv = xr[tau * 4 + 0]; b.uv = xr[tau * 4 + 1];
      c.uv = xr[tau * 4 + 2]; d.uv = xr[tau * 4 + 3];
      FU lo, hb;
      lo.u[0] = pk2(a.f[0], a.f[1]); lo.u[1] = pk2(a.f[2], a.f[3]);
      lo.u[2] = pk2(b.f[0], b.f[1]); lo.u[3] = pk2(b.f[2], b.f[3]);
      hb.u[0] = pk2(c.f[0], c.f[1]); hb.u[1] = pk2(c.f[2], c.f[3]);
      hb.u[2] = pk2(d.f[0], d.f[1]); hb.u[3] = pk2(d.f[2], d.f[3]);
      xlds[sts][(tau * 8 + ksc) * 64 + (rr ^ ksc)] = lo.uv;
      xlds[sts][(tau * 8 + ksc) * 64 + ((rr ^ ksc) | 32)] = hb.uv;
    }
  }
  WAITL;  // ds_writes committed
  __builtin_amdgcn_s_barrier();

  {  // issue wfB (mat1); outstanding <= wfA(9)+wfB(9)
    const u32x4* wb = wf4 + ((1 * 4 + nt) * 9) * 64 + l;
#pragma unroll
    for (int ks = 0; ks < 9; ++ks) wfB[ks].uv = gload(wb + ks * 64);
  }

  FU cf;  // constant frag: 1.0 at k-offset 0 (bias K-step)
  cf.u[0] = hi ? 0u : 0x00003F80u; cf.u[1] = 0; cf.u[2] = 0; cf.u[3] = 0;

  unsigned vpk[8];
  FU kf[2], qf[2];

  // ---- V projection (option A), consumes wfA ----
  WAITV(9);  // wfA drained; wfB in flight
  {
    f32x16 acc = {};
#pragma unroll
    for (int ks = 0; ks < 8; ++ks) {
      FU xf; xf.uv = xlds[ts][(0 * 8 + ks) * 64 + (l ^ ks)];
      acc = __builtin_amdgcn_mfma_f32_32x32x16_bf16(xf.v, wfA[ks].v, acc, 0, 0, 0);
    }
    acc = __builtin_amdgcn_mfma_f32_32x32x16_bf16(cf.v, wfA[8].v, acc, 0, 0, 0);
#pragma unroll
    for (int jv = 0; jv < 8; ++jv) vpk[jv] = pk2(acc[2 * jv], acc[2 * jv + 1]);
  }

  {  // issue wfC (mat2)
    const u32x4* wb = wf4 + ((2 * 4 + nt) * 9) * 64 + l;
#pragma unroll
    for (int ks = 0; ks < 9; ++ks) wfC[ks].uv = gload(wb + ks * 64);
  }

  // ---- K projection (option B: K^T tiles), consumes wfB ----
  WAITV(9);  // wfB drained; wfC in flight
  {
    f32x16 acc = {};
#pragma unroll
    for (int ks = 0; ks < 8; ++ks) {
      FU xf; xf.uv = xlds[ts][(1 * 8 + ks) * 64 + (l ^ ks)];
      acc = __builtin_amdgcn_mfma_f32_32x32x16_bf16(wfB[ks].v, xf.v, acc, 0, 0, 0);
    }
    acc = __builtin_amdgcn_mfma_f32_32x32x16_bf16(wfB[8].v, cf.v, acc, 0, 0, 0);
#pragma unroll
    for (int ch = 0; ch < 2; ++ch) {
      const int c8 = ch * 8;
      xchg(pk2(acc[c8 + 0], acc[c8 + 1]), pk2(acc[c8 + 2], acc[c8 + 3]),
           pk2(acc[c8 + 4], acc[c8 + 5]), pk2(acc[c8 + 6], acc[c8 + 7]), hi, kf[ch].u);
    }
  }

  {  // issue wfD (mat3); covered by Q-proj + attention
    const u32x4* wb = wf4 + ((3 * 4 + nt) * 9) * 64 + l;
#pragma unroll
    for (int ks = 0; ks < 9; ++ks) wfD[ks].uv = gload(wb + ks * 64);
  }

  // ---- Q projection (option B), consumes wfC ----
  WAITV(9);  // wfC drained; wfD in flight
  {
    f32x16 acc = {};
#pragma unroll
    for (int ks = 0; ks < 8; ++ks) {
      FU xf; xf.uv = xlds[ts][(2 * 8 + ks) * 64 + (l ^ ks)];
      acc = __builtin_amdgcn_mfma_f32_32x32x16_bf16(wfC[ks].v, xf.v, acc, 0, 0, 0);
    }
    acc = __builtin_amdgcn_mfma_f32_32x32x16_bf16(wfC[8].v, cf.v, acc, 0, 0, 0);
#pragma unroll
    for (int ch = 0; ch < 2; ++ch) {
      const int c8 = ch * 8;
      xchg(pk2(acc[c8 + 0], acc[c8 + 1]), pk2(acc[c8 + 2], acc[c8 + 3]),
           pk2(acc[c8 + 4], acc[c8 + 5]), pk2(acc[c8 + 6], acc[c8 + 7]), hi, qf[ch].u);
    }
  }

  {  // ---- batch-axis attention for heads 2nt, 2nt+1 ----
    FU vm0, vm1, vs0, vs1;
    xchg(vpk[0], vpk[1], vpk[2], vpk[3], hi, vm0.u);
    xchg(vpk[4], vpk[5], vpk[6], vpk[7], hi, vm1.u);
#pragma unroll
    for (int i = 0; i < 4; ++i) {
      vs0.u[i] = __shfl_xor(vm0.u[i], 16);
      vs1.u[i] = __shfl_xor(vm1.u[i], 16);
    }
#pragma unroll
    for (int ch = 0; ch < 2; ++ch) {
      const int h = nt * 2 + ch;
      const bool own = ((l31 >> 4) == ch);
      f32x16 zz = {};
      f32x16 S = __builtin_amdgcn_mfma_f32_32x32x16_bf16(kf[ch].v, qf[ch].v, zz, 0, 0, 0);
      float mx = S[0];
#pragma unroll
      for (int r = 1; r < 16; ++r) mx = fmaxf(mx, S[r]);
      mx = fmaxf(mx, __shfl_xor(mx, 32));
      float p[16], sum = 0.f;
#pragma unroll
      for (int r = 0; r < 16; ++r) {
        p[r] = exp2f((S[r] - mx) * 1.44269504089f);
        sum += p[r];
      }
      sum += __shfl_xor(sum, 32);
      const float inv = 1.0f / sum;
      FU pf0, pf1;
      xchg(pk2(p[0], p[1]), pk2(p[2], p[3]), pk2(p[4], p[5]), pk2(p[6], p[7]), hi, pf0.u);
      xchg(pk2(p[8], p[9]), pk2(p[10], p[11]), pk2(p[12], p[13]), pk2(p[14], p[15]), hi, pf1.u);
      FU v0, v1;
#pragma unroll
      for (int i = 0; i < 4; ++i) {
        v0.u[i] = own ? vm0.u[i] : vs0.u[i];
        v1.u[i] = own ? vm1.u[i] : vs1.u[i];
      }
      f32x16 z2 = {};
      f32x16 Ot = __builtin_amdgcn_mfma_f32_32x32x16_bf16(v0.v, pf0.v, z2, 0, 0, 0);
      Ot = __builtin_amdgcn_mfma_f32_32x32x16_bf16(v1.v, pf1.v, Ot, 0, 0, 0);
      FU ofr;
      xchg(pk2(Ot[0] * inv, Ot[1] * inv), pk2(Ot[2] * inv, Ot[3] * inv),
           pk2(Ot[4] * inv, Ot[5] * inv), pk2(Ot[6] * inv, Ot[7] * inv), hi, ofr.u);
      olds[ts][h * 64 + l] = ofr.uv;
    }
  }
  WAITL;  // olds writes committed
  __builtin_amdgcn_s_barrier();

  // ---- output projection (option A over 8 head K-steps), consumes wfD ----
  WAITV(0);  // wfD drained
  {
    f32x16 acc = {};
#pragma unroll
    for (int h = 0; h < 8; ++h) {
      FU of; of.uv = olds[ts][h * 64 + l];
      acc = __builtin_amdgcn_mfma_f32_32x32x16_bf16(of.v, wfD[h].v, acc, 0, 0, 0);
    }
    acc = __builtin_amdgcn_mfma_f32_32x32x16_bf16(cf.v, wfD[8].v, acc, 0, 0, 0);
#pragma unroll
    for (int r = 0; r < 16; ++r) {
      const int n = (r & 3) + ((r >> 2) << 3) + (hi << 2);
      out[((long)n * LSEQ + t) * 128 + nt * 32 + l31] = acc[r];
    }
  }
}

extern "C" void kernel_launch(void* const* d_in, const int* in_sizes, int n_in,
                              void* d_out, int out_size, void* d_ws, size_t ws_size,
                              hipStream_t stream) {
  const float* values  = (const float*)d_in[0];
  const float* keys    = (const float*)d_in[1];
  const float* queries = (const float*)d_in[2];
  const float* Wv = (const float*)d_in[3];
  const float* bv = (const float*)d_in[4];
  const float* Wk = (const float*)d_in[5];
  const float* bk = (const float*)d_in[6];
  const float* Wq = (const float*)d_in[7];
  const float* bq = (const float*)d_in[8];
  const float* Wo = (const float*)d_in[9];
  const float* bo = (const float*)d_in[10];

  repack<<<dim3(144), dim3(64), 0, stream>>>(Wv, bv, Wk, bk, Wq, bq, Wo, bo,
                                             (u32x4*)d_ws);
  fused_mha<<<dim3(GRID), dim3(512), 0, stream>>>(
      values, keys, queries, (const u32x4*)d_ws, (float*)d_out);
}